// Round 1
// baseline (181.754 us; speedup 1.0000x reference)
//
#include <hip/hip_runtime.h>

// Problem constants
constexpr int D_ = 128, H_ = 60, W_ = 108, HW_ = 6480;

// Workspace layout (float offsets). Features stored position-major [pos][128].
constexpr size_t O_F0T  = 0;         // fmap0 level0 transposed [6480][128]
constexpr size_t O_F1T  = 829440;    // fmap1 level0 transposed
constexpr size_t O_F0L1 = 1658880;   // pooled fmap0 level1 [30*54][128]
constexpr size_t O_F0L2 = 1866240;   // level2 [15*27][128]
constexpr size_t O_F0L3 = 1918080;   // level3 [7*13][128]
constexpr size_t O_F1L1 = 1929728;
constexpr size_t O_F1L2 = 2137088;
constexpr size_t O_F1L3 = 2188928;
// total = 2,200,576 floats = 8.8 MB

// ---------------------------------------------------------------------------
// Transpose [128][6480] -> [6480][128], both fmaps (blockIdx.y selects map).
__global__ __launch_bounds__(256) void k_transpose(const float* __restrict__ f0,
                                                   const float* __restrict__ f1,
                                                   float* __restrict__ ws) {
    __shared__ float lds[64 * 129];   // +1 pad breaks bank conflicts
    const float* src = (blockIdx.y == 0) ? f0 : f1;
    float* dst = ws + ((blockIdx.y == 0) ? O_F0T : O_F1T);
    const int p0 = blockIdx.x * 64;
    const int t  = threadIdx.x;
    const int pr = t & 63, cr = t >> 6;     // read mapping: 64 positions x 4 ch
    #pragma unroll
    for (int cb = 0; cb < 128; cb += 4) {
        int c = cb + cr, p = p0 + pr;
        if (p < HW_) lds[pr * 129 + c] = src[(size_t)c * HW_ + p];
    }
    __syncthreads();
    const int cw = t & 127, pw = t >> 7;    // write mapping: 2 positions x 128 ch
    #pragma unroll
    for (int pb = 0; pb < 64; pb += 2) {
        int p = p0 + pb + pw;
        if (p < HW_) dst[(size_t)p * 128 + cw] = lds[(pb + pw) * 129 + cw];
    }
}

// ---------------------------------------------------------------------------
// 2x2 avg pool, position-major layout, floor semantics. blockIdx.y selects map.
__global__ __launch_bounds__(256) void k_pool(float* __restrict__ ws,
                                              int win, int hout, int wout,
                                              size_t offA_in, size_t offA_out,
                                              size_t offB_in, size_t offB_out) {
    const size_t off_in  = (blockIdx.y == 0) ? offA_in  : offB_in;
    const size_t off_out = (blockIdx.y == 0) ? offA_out : offB_out;
    const int idx = blockIdx.x * 256 + threadIdx.x;
    const int total = hout * wout * 32;
    if (idx >= total) return;
    const int pos = idx >> 5, q = idx & 31;
    const int y = pos / wout, x = pos - y * wout;
    const float* in = ws + off_in;
    float* out = ws + off_out;
    const float4 va = ((const float4*)(in + (size_t)(2*y*win + 2*x    ) * 128))[q];
    const float4 vb = ((const float4*)(in + (size_t)(2*y*win + 2*x + 1) * 128))[q];
    const float4 vc = ((const float4*)(in + (size_t)((2*y+1)*win + 2*x    ) * 128))[q];
    const float4 vd = ((const float4*)(in + (size_t)((2*y+1)*win + 2*x + 1) * 128))[q];
    float4 r;
    r.x = (va.x + vb.x + vc.x + vd.x) * 0.25f;
    r.y = (va.y + vb.y + vc.y + vd.y) * 0.25f;
    r.z = (va.z + vb.z + vc.z + vd.z) * 0.25f;
    r.w = (va.w + vb.w + vc.w + vd.w) * 0.25f;
    ((float4*)(out + (size_t)pos * 128))[q] = r;
}

// ---------------------------------------------------------------------------
// Lookup: one block per (pixel, direction). Thread t computes one 128-dim dot
// for (level = t/64, grid point = t%64 of the 8x8 integer window grid), then
// threads 0..195 do the bilinear combines and write the 196 channels.
__global__ __launch_bounds__(256) void k_lookup(const float* __restrict__ ws,
                                                const float* __restrict__ flow0,
                                                const float* __restrict__ flow1,
                                                const float* __restrict__ embt,
                                                float* __restrict__ out) {
    __shared__ float sfeat[128];
    __shared__ float dots[4 * 64];

    const int pix = blockIdx.x;
    const int dir = blockIdx.y;
    const int h = pix / W_, w = pix - h * W_;
    const int t = threadIdx.x;

    const float e = embt[0];
    const float scale = (dir == 0) ? (1.0f / e) : (1.0f / (1.0f - e));
    const float* fl = (dir == 0) ? flow1 : flow0;
    const float cx = (float)w + fl[pix] * scale;
    const float cy = (float)h + fl[HW_ + pix] * scale;

    // stage the source feature (dir0: fmap0 pixel feature; dir1: fmap1)
    const size_t srcoff = ((dir == 0) ? O_F0T : O_F1T) + (size_t)pix * 128;
    if (t < 32) ((float4*)sfeat)[t] = ((const float4*)(ws + srcoff))[t];
    __syncthreads();

    {
        const int lvl = t >> 6, r = t & 63, j = r >> 3, i = r & 7;
        size_t doff;
        if (dir == 0)
            doff = (lvl == 0) ? O_F1T : (lvl == 1) ? O_F1L1 : (lvl == 2) ? O_F1L2 : O_F1L3;
        else
            doff = (lvl == 0) ? O_F0T : (lvl == 1) ? O_F0L1 : (lvl == 2) ? O_F0L2 : O_F0L3;
        const int wl = 108 >> lvl;   // 108,54,27,13
        const int hl = 60 >> lvl;    // 60,30,15,7
        const float invl = (lvl == 0) ? 1.0f : (lvl == 1) ? 0.5f : (lvl == 2) ? 0.25f : 0.125f;
        const float cxl = cx * invl, cyl = cy * invl;
        const int bx = (int)floorf(cxl), by = (int)floorf(cyl);
        const int gx = bx - 3 + i, gy = by - 3 + j;

        float dot = 0.0f;
        if (gx >= 0 && gx < wl && gy >= 0 && gy < hl) {
            const float4* __restrict__ fp =
                (const float4*)(ws + doff + (size_t)(gy * wl + gx) * 128);
            const float4* sp = (const float4*)sfeat;
            float s0 = 0.f, s1 = 0.f, s2 = 0.f, s3 = 0.f;
            #pragma unroll 8
            for (int q = 0; q < 32; ++q) {
                float4 f = fp[q];
                float4 s = sp[q];
                s0 = fmaf(f.x, s.x, s0);
                s1 = fmaf(f.y, s.y, s1);
                s2 = fmaf(f.z, s.z, s2);
                s3 = fmaf(f.w, s.w, s3);
            }
            dot = (s0 + s1) + (s2 + s3);
        }
        dots[t] = dot * 0.08838834764831845f;   // 1/sqrt(128)
    }
    __syncthreads();

    if (t < 196) {
        const int lv = t / 49;
        const int k = t - lv * 49;
        const int dyi = k / 7, dxi = k - dyi * 7;
        const float iv = (lv == 0) ? 1.0f : (lv == 1) ? 0.5f : (lv == 2) ? 0.25f : 0.125f;
        const float cxl = cx * iv, cyl = cy * iv;
        const float fx = cxl - floorf(cxl);
        const float fy = cyl - floorf(cyl);
        const float* dl = dots + lv * 64;
        const float d00 = dl[dyi * 8 + dxi];
        const float d01 = dl[dyi * 8 + dxi + 1];
        const float d10 = dl[dyi * 8 + dxi + 8];
        const float d11 = dl[dyi * 8 + dxi + 9];
        const float v = (d00 * (1.0f - fx) + d01 * fx) * (1.0f - fy) +
                        (d10 * (1.0f - fx) + d11 * fx) * fy;
        out[(size_t)(dir * 196 + t) * HW_ + pix] = v;
    } else if (dir == 0 && t < 200) {
        const int c = t - 196;   // flow channels: flow0[0],flow0[1],flow1[0],flow1[1]
        const float v = (c < 2) ? flow0[(size_t)c * HW_ + pix]
                                : flow1[(size_t)(c - 2) * HW_ + pix];
        out[(size_t)(392 + c) * HW_ + pix] = v;
    }
}

// ---------------------------------------------------------------------------
extern "C" void kernel_launch(void* const* d_in, const int* in_sizes, int n_in,
                              void* d_out, int out_size, void* d_ws, size_t ws_size,
                              hipStream_t stream) {
    const float* fmap0 = (const float*)d_in[0];
    const float* fmap1 = (const float*)d_in[1];
    const float* flow0 = (const float*)d_in[2];
    const float* flow1 = (const float*)d_in[3];
    const float* embt  = (const float*)d_in[4];
    float* ws  = (float*)d_ws;
    float* out = (float*)d_out;

    // 1) transpose both fmaps to position-major
    k_transpose<<<dim3(102, 2), 256, 0, stream>>>(fmap0, fmap1, ws);
    // 2) feature pyramids (pooling commutes with the channel dot)
    k_pool<<<dim3(203, 2), 256, 0, stream>>>(ws, 108, 30, 54, O_F0T,  O_F0L1, O_F1T,  O_F1L1);
    k_pool<<<dim3(51, 2),  256, 0, stream>>>(ws,  54, 15, 27, O_F0L1, O_F0L2, O_F1L1, O_F1L2);
    k_pool<<<dim3(12, 2),  256, 0, stream>>>(ws,  27,  7, 13, O_F0L2, O_F0L3, O_F1L2, O_F1L3);
    // 3) per-(pixel, direction) window dots + bilinear combine + flow passthrough
    k_lookup<<<dim3(6480, 2), 256, 0, stream>>>(ws, flow0, flow1, embt, out);
}

// Round 2
// 166.322 us; speedup vs baseline: 1.0928x; 1.0928x over previous
//
#include <hip/hip_runtime.h>

typedef _Float16 h16;
typedef __attribute__((ext_vector_type(8))) h16 h8v;
typedef __attribute__((ext_vector_type(2))) h16 h2v;

constexpr int H_ = 60, W_ = 108, HW_ = 6480;

// Workspace layout in HALF elements, position-major [pos][128].
constexpr size_t O_F0T  = 0;
constexpr size_t O_F1T  = 829440;
constexpr size_t O_F0L1 = 1658880;   // 30*54 pos
constexpr size_t O_F0L2 = 1866240;   // 15*27
constexpr size_t O_F0L3 = 1918080;   // 7*13
constexpr size_t O_F1L1 = 1929728;
constexpr size_t O_F1L2 = 2137088;
constexpr size_t O_F1L3 = 2188928;
// total 2,200,576 halves = 4.4 MB

// ---------------------------------------------------------------------------
// Transpose [128][6480] f32 -> [6480][128] f16, both maps (blockIdx.y).
__global__ __launch_bounds__(256) void k_transpose(const float* __restrict__ f0,
                                                   const float* __restrict__ f1,
                                                   h16* __restrict__ ws) {
    __shared__ float lds[64 * 129];
    const float* src = blockIdx.y ? f1 : f0;
    h16* dst = ws + (blockIdx.y ? O_F1T : O_F0T);
    const int p0 = blockIdx.x * 64;
    const int t  = threadIdx.x;
    const int pr = t & 63, cr = t >> 6;
    #pragma unroll
    for (int cb = 0; cb < 128; cb += 4) {
        int c = cb + cr, p = p0 + pr;
        if (p < HW_) lds[pr * 129 + c] = src[(size_t)c * HW_ + p];
    }
    __syncthreads();
    const int cw = t & 63, pw = t >> 6;     // cw indexes half2 pairs
    #pragma unroll
    for (int pb = 0; pb < 64; pb += 4) {
        int p = p0 + pb + pw;
        if (p < HW_) {
            float a = lds[(pb + pw) * 129 + 2 * cw];
            float b = lds[(pb + pw) * 129 + 2 * cw + 1];
            h2v v; v.x = (h16)a; v.y = (h16)b;
            ((h2v*)dst)[(size_t)p * 64 + cw] = v;
        }
    }
}

// ---------------------------------------------------------------------------
// 2x2 avg pool in position-major fp16 (fp32 accumulate). blockIdx.y = map.
__global__ __launch_bounds__(256) void k_pool(h16* __restrict__ ws,
                                              int win, int hout, int wout,
                                              size_t iA, size_t oA,
                                              size_t iB, size_t oB) {
    const size_t off_in  = blockIdx.y ? iB : iA;
    const size_t off_out = blockIdx.y ? oB : oA;
    const int idx = blockIdx.x * 256 + threadIdx.x;
    const int total = hout * wout * 16;
    if (idx >= total) return;
    const int pos = idx >> 4, q = idx & 15;
    const int y = pos / wout, x = pos - y * wout;
    const h8v* r0 = (const h8v*)(ws + off_in + (size_t)(2*y*win + 2*x) * 128);
    const h8v* r2 = (const h8v*)(ws + off_in + (size_t)((2*y+1)*win + 2*x) * 128);
    h8v a = r0[q], b = r0[q + 16], c = r2[q], d = r2[q + 16], o;
    #pragma unroll
    for (int j = 0; j < 8; ++j)
        o[j] = (h16)((((float)a[j] + (float)b[j]) + ((float)c[j] + (float)d[j])) * 0.25f);
    ((h8v*)(ws + off_out + (size_t)pos * 128))[q] = o;
}

// ---------------------------------------------------------------------------
#if __has_builtin(__builtin_amdgcn_fdot2)
__device__ __forceinline__ float dot8(h8v f, h8v s, float acc) {
    acc = __builtin_amdgcn_fdot2(__builtin_shufflevector(f, f, 0, 1),
                                 __builtin_shufflevector(s, s, 0, 1), acc, false);
    acc = __builtin_amdgcn_fdot2(__builtin_shufflevector(f, f, 2, 3),
                                 __builtin_shufflevector(s, s, 2, 3), acc, false);
    acc = __builtin_amdgcn_fdot2(__builtin_shufflevector(f, f, 4, 5),
                                 __builtin_shufflevector(s, s, 4, 5), acc, false);
    acc = __builtin_amdgcn_fdot2(__builtin_shufflevector(f, f, 6, 7),
                                 __builtin_shufflevector(s, s, 6, 7), acc, false);
    return acc;
}
#else
__device__ __forceinline__ float dot8(h8v f, h8v s, float acc) {
    #pragma unroll
    for (int j = 0; j < 8; ++j) acc = fmaf((float)f[j], (float)s[j], acc);
    return acc;
}
#endif

// Lookup: block = (8-pixel tile, dir) with XCD-affinity decode.
// xcd = bid&7: xcd 0..3 -> dir0, 4..7 -> dir1; contiguous ord chunk per xcd.
__global__ __launch_bounds__(256) void k_lookup(const h16* __restrict__ ws,
                                                const float* __restrict__ flow0,
                                                const float* __restrict__ flow1,
                                                const float* __restrict__ embt,
                                                float* __restrict__ out) {
    __shared__ alignas(16) h16 sfeat[2][128];
    __shared__ float dots[256];

    const int bid = blockIdx.x;
    const int xcd = bid & 7;
    const int dir = xcd >> 2;
    const int ord = (xcd & 3) * 203 + (bid >> 3);   // contiguous chunk per xcd
    if (ord >= 810) return;
    const int pix0 = ord * 8;
    const int t = threadIdx.x;

    const float e = embt[0];
    const float scale = dir ? 1.0f / (1.0f - e) : 1.0f / e;
    const float* fl = dir ? flow0 : flow1;

    const int lvl = t >> 6, r = t & 63, wj = r >> 3, wi = r & 7;
    const size_t goff = dir
        ? ((lvl == 0) ? O_F0T : (lvl == 1) ? O_F0L1 : (lvl == 2) ? O_F0L2 : O_F0L3)
        : ((lvl == 0) ? O_F1T : (lvl == 1) ? O_F1L1 : (lvl == 2) ? O_F1L2 : O_F1L3);
    const size_t soff = dir ? O_F1T : O_F0T;
    const int wl = 108 >> lvl, hl = 60 >> lvl;
    const float invl = (lvl == 0) ? 1.f : (lvl == 1) ? 0.5f : (lvl == 2) ? 0.25f : 0.125f;

    float vals[8];

    if (t < 16)
        ((float4*)sfeat[0])[t] = ((const float4*)(ws + soff + (size_t)pix0 * 128))[t];
    __syncthreads();

    #pragma unroll
    for (int p = 0; p < 8; ++p) {
        const int pix = pix0 + p;
        const int h = pix / 108, w = pix - h * 108;
        const float cx = (float)w + fl[pix] * scale;
        const float cy = (float)h + fl[HW_ + pix] * scale;

        {   // one 128-dot per thread: (level, 8x8 integer grid point)
            const float cxl = cx * invl, cyl = cy * invl;
            const int gx = (int)floorf(cxl) - 3 + wi;
            const int gy = (int)floorf(cyl) - 3 + wj;
            float acc = 0.0f;
            if (gx >= 0 && gx < wl && gy >= 0 && gy < hl) {
                const h8v* __restrict__ fp =
                    (const h8v*)(ws + goff + (size_t)(gy * wl + gx) * 128);
                const h8v* sp = (const h8v*)sfeat[p & 1];
                #pragma unroll
                for (int q = 0; q < 16; ++q) acc = dot8(fp[q], sp[q], acc);
            }
            dots[t] = acc * 0.08838834764831845f;   // 1/sqrt(128)
        }
        __syncthreads();

        if (t < 196) {
            const int lv = t / 49, k = t - lv * 49;
            const int dyi = k / 7, dxi = k - dyi * 7;
            const float iv = (lv == 0) ? 1.f : (lv == 1) ? 0.5f : (lv == 2) ? 0.25f : 0.125f;
            const float cxl = cx * iv, cyl = cy * iv;
            const float fx = cxl - floorf(cxl), fy = cyl - floorf(cyl);
            const float* dl = dots + lv * 64;
            const float d00 = dl[dyi * 8 + dxi];
            const float d01 = dl[dyi * 8 + dxi + 1];
            const float d10 = dl[dyi * 8 + dxi + 8];
            const float d11 = dl[dyi * 8 + dxi + 9];
            vals[p] = (d00 * (1.0f - fx) + d01 * fx) * (1.0f - fy) +
                      (d10 * (1.0f - fx) + d11 * fx) * fy;
        } else if (t >= 240) {
            if (p < 7)   // prefetch next pixel's source feature
                ((float4*)sfeat[(p + 1) & 1])[t - 240] =
                    ((const float4*)(ws + soff + (size_t)(pix0 + p + 1) * 128))[t - 240];
        } else if (dir == 0 && t < 200) {
            const int c = t - 196;
            vals[p] = (c < 2) ? flow0[(size_t)c * HW_ + pix]
                              : flow1[(size_t)(c - 2) * HW_ + pix];
        }
        __syncthreads();
    }

    // coalesced register->global writes: 32B contiguous per thread
    if (t < 196) {
        float* o = out + (size_t)(dir * 196 + t) * HW_ + pix0;
        ((float4*)o)[0] = make_float4(vals[0], vals[1], vals[2], vals[3]);
        ((float4*)o)[1] = make_float4(vals[4], vals[5], vals[6], vals[7]);
    } else if (dir == 0 && t < 200) {
        float* o = out + (size_t)(392 + t - 196) * HW_ + pix0;
        ((float4*)o)[0] = make_float4(vals[0], vals[1], vals[2], vals[3]);
        ((float4*)o)[1] = make_float4(vals[4], vals[5], vals[6], vals[7]);
    }
}

// ---------------------------------------------------------------------------
extern "C" void kernel_launch(void* const* d_in, const int* in_sizes, int n_in,
                              void* d_out, int out_size, void* d_ws, size_t ws_size,
                              hipStream_t stream) {
    const float* fmap0 = (const float*)d_in[0];
    const float* fmap1 = (const float*)d_in[1];
    const float* flow0 = (const float*)d_in[2];
    const float* flow1 = (const float*)d_in[3];
    const float* embt  = (const float*)d_in[4];
    h16* ws  = (h16*)d_ws;
    float* out = (float*)d_out;

    k_transpose<<<dim3(102, 2), 256, 0, stream>>>(fmap0, fmap1, ws);
    k_pool<<<dim3(102, 2), 256, 0, stream>>>(ws, 108, 30, 54, O_F0T,  O_F0L1, O_F1T,  O_F1L1);
    k_pool<<<dim3(26, 2),  256, 0, stream>>>(ws,  54, 15, 27, O_F0L1, O_F0L2, O_F1L1, O_F1L2);
    k_pool<<<dim3(6, 2),   256, 0, stream>>>(ws,  27,  7, 13, O_F0L2, O_F0L3, O_F1L2, O_F1L3);
    k_lookup<<<dim3(203 * 8), 256, 0, stream>>>(ws, flow0, flow1, embt, out);
}

// Round 3
// 54.461 us; speedup vs baseline: 3.3373x; 3.0540x over previous
//
#include <hip/hip_runtime.h>

typedef _Float16 h16;
typedef __attribute__((ext_vector_type(8))) h16 h8v;
typedef __attribute__((ext_vector_type(2))) h16 h2v;

constexpr int H_ = 60, W_ = 108, HW_ = 6480;

// Workspace layout in HALF elements, position-major [pos][128].
constexpr size_t O_F0T  = 0;
constexpr size_t O_F1T  = 829440;
constexpr size_t O_F0L1 = 1658880;   // 30*54 pos
constexpr size_t O_F0L2 = 1866240;   // 15*27
constexpr size_t O_F0L3 = 1918080;   // 7*13
constexpr size_t O_F1L1 = 1929728;
constexpr size_t O_F1L2 = 2137088;
constexpr size_t O_F1L3 = 2188928;

// ---------------------------------------------------------------------------
// Transpose [128][6480] f32 -> [6480][128] f16, both maps (blockIdx.y).
__global__ __launch_bounds__(256) void k_transpose(const float* __restrict__ f0,
                                                   const float* __restrict__ f1,
                                                   h16* __restrict__ ws) {
    __shared__ float lds[64 * 129];
    const float* src = blockIdx.y ? f1 : f0;
    h16* dst = ws + (blockIdx.y ? O_F1T : O_F0T);
    const int p0 = blockIdx.x * 64;
    const int t  = threadIdx.x;
    const int pr = t & 63, cr = t >> 6;
    #pragma unroll
    for (int cb = 0; cb < 128; cb += 4) {
        int c = cb + cr, p = p0 + pr;
        if (p < HW_) lds[pr * 129 + c] = src[(size_t)c * HW_ + p];
    }
    __syncthreads();
    const int cw = t & 63, pw = t >> 6;     // cw indexes half2 pairs
    #pragma unroll
    for (int pb = 0; pb < 64; pb += 4) {
        int p = p0 + pb + pw;
        if (p < HW_) {
            float a = lds[(pb + pw) * 129 + 2 * cw];
            float b = lds[(pb + pw) * 129 + 2 * cw + 1];
            h2v v; v.x = (h16)a; v.y = (h16)b;
            ((h2v*)dst)[(size_t)p * 64 + cw] = v;
        }
    }
}

// ---------------------------------------------------------------------------
// 2x2 avg pool in position-major fp16 (fp32 accumulate). blockIdx.y = map.
__global__ __launch_bounds__(256) void k_pool(h16* __restrict__ ws,
                                              int win, int hout, int wout,
                                              size_t iA, size_t oA,
                                              size_t iB, size_t oB) {
    const size_t off_in  = blockIdx.y ? iB : iA;
    const size_t off_out = blockIdx.y ? oB : oA;
    const int idx = blockIdx.x * 256 + threadIdx.x;
    const int total = hout * wout * 16;
    if (idx >= total) return;
    const int pos = idx >> 4, q = idx & 15;
    const int y = pos / wout, x = pos - y * wout;
    const h8v* r0 = (const h8v*)(ws + off_in + (size_t)(2*y*win + 2*x) * 128);
    const h8v* r2 = (const h8v*)(ws + off_in + (size_t)((2*y+1)*win + 2*x) * 128);
    h8v a = r0[q], b = r0[q + 16], c = r2[q], d = r2[q + 16], o;
    #pragma unroll
    for (int j = 0; j < 8; ++j)
        o[j] = (h16)((((float)a[j] + (float)b[j]) + ((float)c[j] + (float)d[j])) * 0.25f);
    ((h8v*)(ws + off_out + (size_t)pos * 128))[q] = o;
}

// ---------------------------------------------------------------------------
#if __has_builtin(__builtin_amdgcn_fdot2)
__device__ __forceinline__ float dot8(h8v f, h8v s, float acc) {
    acc = __builtin_amdgcn_fdot2(__builtin_shufflevector(f, f, 0, 1),
                                 __builtin_shufflevector(s, s, 0, 1), acc, false);
    acc = __builtin_amdgcn_fdot2(__builtin_shufflevector(f, f, 2, 3),
                                 __builtin_shufflevector(s, s, 2, 3), acc, false);
    acc = __builtin_amdgcn_fdot2(__builtin_shufflevector(f, f, 4, 5),
                                 __builtin_shufflevector(s, s, 4, 5), acc, false);
    acc = __builtin_amdgcn_fdot2(__builtin_shufflevector(f, f, 6, 7),
                                 __builtin_shufflevector(s, s, 6, 7), acc, false);
    return acc;
}
#else
__device__ __forceinline__ float dot8(h8v f, h8v s, float acc) {
    #pragma unroll
    for (int j = 0; j < 8; ++j) acc = fmaf((float)f[j], (float)s[j], acc);
    return acc;
}
#endif

// ---------------------------------------------------------------------------
// One WAVE per (pixel, dir). No LDS, no barriers. Per level: 8 coalesced
// 2KB row loads (lane = (pos p = L>>3, chan-slice ch = L&7)), per-lane
// 16-ch partial dot, 8-lane shfl_xor reduce, lane 8p+j keeps dot(row j,
// col p), 4 dynamic shuffles for the bilinear taps.
__global__ __launch_bounds__(256) void k_lookup(const h16* __restrict__ ws,
                                                const float* __restrict__ flow0,
                                                const float* __restrict__ flow1,
                                                const float* __restrict__ embt,
                                                float* __restrict__ out) {
    const int bid = blockIdx.x;
    const int xcd = bid & 7;
    const int dir = xcd >> 2;                      // XCDs 0-3: dir0, 4-7: dir1
    const int ord = (xcd & 3) * 405 + (bid >> 3);  // contiguous pixel chunk/XCD
    const int t = threadIdx.x;
    const int L = t & 63;
    const int pix = ord * 4 + (t >> 6);            // one pixel per wave
    const int h = pix / 108, w = pix - h * 108;

    const float e = embt[0];
    const float scale = dir ? 1.0f / (1.0f - e) : 1.0f / e;
    const float* fl = dir ? flow0 : flow1;
    const float cx = (float)w + fl[pix] * scale;
    const float cy = (float)h + fl[HW_ + pix] * scale;

    const int ch = L & 7;        // 16-channel slice index
    const int p  = L >> 3;       // window column 0..7

    // per-lane source-feature slice (8 lanes share each address -> broadcast)
    const size_t soff = (dir ? O_F1T : O_F0T) + (size_t)pix * 128;
    const h8v sf0 = ((const h8v*)(ws + soff))[2 * ch];
    const h8v sf1 = ((const h8v*)(ws + soff))[2 * ch + 1];

    const size_t offs_d0[4] = {O_F1T, O_F1L1, O_F1L2, O_F1L3};
    const size_t offs_d1[4] = {O_F0T, O_F0L1, O_F0L2, O_F0L3};
    const float invs[4] = {1.0f, 0.5f, 0.25f, 0.125f};

    float outv[4];

    #pragma unroll
    for (int lvl = 0; lvl < 4; ++lvl) {
        const size_t goff = dir ? offs_d1[lvl] : offs_d0[lvl];
        const int wl = 108 >> lvl, hl = 60 >> lvl;
        const float cxl = cx * invs[lvl], cyl = cy * invs[lvl];
        const float bxf = floorf(cxl), byf = floorf(cyl);
        const int bx = (int)bxf, by = (int)byf;
        const int gx = bx - 3 + p;
        const int gxc = min(max(gx, 0), wl - 1);
        const bool gxv = (gx >= 0) & (gx < wl);

        // issue all 8 coalesced row loads (clamped addresses keep coalescing)
        h8v r0[8], r1[8];
        #pragma unroll
        for (int j = 0; j < 8; ++j) {
            const int gy = by - 3 + j;
            const int gyc = min(max(gy, 0), hl - 1);
            const h8v* rp = (const h8v*)(ws + goff + (size_t)(gyc * wl + gxc) * 128);
            r0[j] = rp[2 * ch];
            r1[j] = rp[2 * ch + 1];
        }

        float dval = 0.0f;
        #pragma unroll
        for (int j = 0; j < 8; ++j) {
            const int gy = by - 3 + j;
            const bool v = gxv & (gy >= 0) & (gy < hl);
            float acc = dot8(r1[j], sf1, dot8(r0[j], sf0, 0.0f));
            acc += __shfl_xor(acc, 1);
            acc += __shfl_xor(acc, 2);
            acc += __shfl_xor(acc, 4);
            acc = v ? acc * 0.08838834764831845f : 0.0f;  // 1/sqrt(128)
            if (ch == j) dval = acc;   // lane 8p+j <- dot(row j, col p)
        }

        // bilinear: lane k<49 -> output (dyi,dxi); tap (gy,gx) lives in lane 8*gx+gy
        const int dyi = L / 7, dxi = L - dyi * 7;  // valid for L<49
        const float fx = cxl - bxf, fy = cyl - byf;
        const float d00 = __shfl(dval, 8 * dxi + dyi);
        const float d01 = __shfl(dval, 8 * dxi + dyi + 8);
        const float d10 = __shfl(dval, 8 * dxi + dyi + 1);
        const float d11 = __shfl(dval, 8 * dxi + dyi + 9);
        outv[lvl] = (d00 * (1.0f - fx) + d01 * fx) * (1.0f - fy) +
                    (d10 * (1.0f - fx) + d11 * fx) * fy;
    }

    if (L < 49) {
        #pragma unroll
        for (int lvl = 0; lvl < 4; ++lvl)
            out[(size_t)(dir * 196 + lvl * 49 + L) * HW_ + pix] = outv[lvl];
    } else if (dir == 0 && L >= 56 && L < 60) {
        const int c = L - 56;
        out[(size_t)(392 + c) * HW_ + pix] =
            (c < 2) ? flow0[(size_t)c * HW_ + pix]
                    : flow1[(size_t)(c - 2) * HW_ + pix];
    }
}

// ---------------------------------------------------------------------------
extern "C" void kernel_launch(void* const* d_in, const int* in_sizes, int n_in,
                              void* d_out, int out_size, void* d_ws, size_t ws_size,
                              hipStream_t stream) {
    const float* fmap0 = (const float*)d_in[0];
    const float* fmap1 = (const float*)d_in[1];
    const float* flow0 = (const float*)d_in[2];
    const float* flow1 = (const float*)d_in[3];
    const float* embt  = (const float*)d_in[4];
    h16* ws  = (h16*)d_ws;
    float* out = (float*)d_out;

    k_transpose<<<dim3(102, 2), 256, 0, stream>>>(fmap0, fmap1, ws);
    k_pool<<<dim3(102, 2), 256, 0, stream>>>(ws, 108, 30, 54, O_F0T,  O_F0L1, O_F1T,  O_F1L1);
    k_pool<<<dim3(26, 2),  256, 0, stream>>>(ws,  54, 15, 27, O_F0L1, O_F0L2, O_F1L1, O_F1L2);
    k_pool<<<dim3(6, 2),   256, 0, stream>>>(ws,  27,  7, 13, O_F0L2, O_F0L3, O_F1L2, O_F1L3);
    k_lookup<<<dim3(405 * 8), 256, 0, stream>>>(ws, flow0, flow1, embt, out);
}